// Round 5
// baseline (3026.493 us; speedup 1.0000x reference)
//
#include <hip/hip_runtime.h>
#include <hip/hip_bf16.h>

// Problem constants (from reference)
#define BB    512
#define TT    128
#define HID   1024
#define EMBD  512
#define VOC   1024
#define OUTN  1024
#define DIMG  2048
#define FOURH 4096

typedef __attribute__((ext_vector_type(8))) short  short8;   // 8 bf16 = 4 VGPRs (MFMA A/B frag)
typedef __attribute__((ext_vector_type(4))) float  f32x4;    // MFMA C/D frag

// Gate-interleaved column map: n' = G*64 + gate*16 + u  ->  original col = gate*1024 + G*16 + u
__device__ __forceinline__ int lstm_colmap(int n) {
    return ((n >> 4) & 3) * HID + ((n >> 6) << 4) + (n & 15);
}

__device__ __forceinline__ float sigmoidf_(float x) { return 1.0f / (1.0f + expf(-x)); }

__device__ __forceinline__ short f2bf(float x) {
    __hip_bfloat16 b = __float2bfloat16(x);
    return *(short*)&b;
}
__device__ __forceinline__ float bf2f(short s) {
    __hip_bfloat16 b;
    *(short*)&b = s;
    return __bfloat162float(b);
}

// ---------------------------------------------------------------------------
// Zero-init c (f32) and h0 (bf16)
__global__ void init_k(float* __restrict__ c, short* __restrict__ h0, int n) {
    int i = blockIdx.x * blockDim.x + threadIdx.x;
    if (i < n) { c[i] = 0.0f; h0[i] = 0; }
}

// ---------------------------------------------------------------------------
// Wh_t[n'][k] = bf16(Wcell_h[k][colmap(n')])   f32 -> bf16, gate-interleaved
__global__ void build_wht_k(const float* __restrict__ Wc_h, short* __restrict__ out, int total) {
    int tid = blockIdx.x * blockDim.x + threadIdx.x;
    if (tid >= total) return;
    int n = tid >> 10;          // n' in [0, 4096)
    int k = tid & 1023;         // k  in [0, 1024)
    out[tid] = f2bf(Wc_h[(size_t)k * FOURH + lstm_colmap(n)]);
}

// ---------------------------------------------------------------------------
// One-shot GEMM: out[M,N] = A[M,K] @ B[K,N](f32, original layout) + bias(f32)
// A is f32 (converted in staging) or bf16 (short). B staged with in-LDS
// transpose+bf16 convert; optional gate-interleave column map (MAPN).
// OutT = float (harness output) or short (bf16 internal, e.g. eproj).
// Tile 64x128, 256 threads = 4 waves (2x2), each wave 32x64 via 2x4 MFMA 16x16x32.
template<typename AT, typename OutT, bool MAPN>
__global__ __launch_bounds__(256) void gemm_f32b_k(
    const AT* __restrict__ A, const float* __restrict__ B,
    const float* __restrict__ bias, OutT* __restrict__ out,
    int K, int N, int ldb)
{
    __shared__ __align__(16) short As[64 * 40];    // [64][32+8]
    __shared__ __align__(16) short Bs[128 * 40];   // [128][32+8]
    const int tid  = threadIdx.x;
    const int lane = tid & 63;
    const int wid  = tid >> 6;
    const int wm = wid >> 1, wn = wid & 1;
    const int col16 = lane & 15, quad = lane >> 4;
    const int m0 = blockIdx.y * 64;
    const int n0 = blockIdx.x * 128;

    f32x4 acc[2][4];
#pragma unroll
    for (int i = 0; i < 2; i++)
#pragma unroll
        for (int j = 0; j < 4; j++) acc[i][j] = (f32x4)0.0f;

    const int arow = tid >> 2, aq = tid & 3;           // A tile: 64 rows x (4x8) k
    const int bkk  = tid >> 3, bng = (tid & 7) * 16;   // B tile: 32 k-rows x (8x16) n
    // column base in ORIGINAL B for this thread's 16-col group (affine within 16-blocks)
    const int nprime = n0 + bng;
    const int bcol = MAPN ? (((nprime >> 4) & 3) * HID + ((nprime >> 6) << 4)) : nprime;

    for (int k0 = 0; k0 < K; k0 += 32) {
        // ---- A staging (8 elems/thread) ----
        short8 av;
        if constexpr (__is_same(AT, float)) {
            const float* ap = A + (size_t)(m0 + arow) * K + k0 + aq * 8;
            float4 a0 = *(const float4*)ap;
            float4 a1 = *(const float4*)(ap + 4);
            av = short8{ f2bf(a0.x), f2bf(a0.y), f2bf(a0.z), f2bf(a0.w),
                         f2bf(a1.x), f2bf(a1.y), f2bf(a1.z), f2bf(a1.w) };
        } else {
            av = *(const short8*)(A + (size_t)(m0 + arow) * K + k0 + aq * 8);
        }
        // ---- B staging: 16 f32 (one k-row, 16 cols), convert, transpose-store ----
        const float* bp = B + (size_t)(k0 + bkk) * ldb + bcol;
        float4 b0 = *(const float4*)(bp + 0);
        float4 b1 = *(const float4*)(bp + 4);
        float4 b2 = *(const float4*)(bp + 8);
        float4 b3 = *(const float4*)(bp + 12);
        short bs16[16] = { f2bf(b0.x), f2bf(b0.y), f2bf(b0.z), f2bf(b0.w),
                           f2bf(b1.x), f2bf(b1.y), f2bf(b1.z), f2bf(b1.w),
                           f2bf(b2.x), f2bf(b2.y), f2bf(b2.z), f2bf(b2.w),
                           f2bf(b3.x), f2bf(b3.y), f2bf(b3.z), f2bf(b3.w) };
        *(short8*)&As[arow * 40 + aq * 8] = av;
#pragma unroll
        for (int j = 0; j < 16; j++)
            Bs[(bng + j) * 40 + bkk] = bs16[j];
        __syncthreads();

        short8 afrag[2], bfrag[4];
#pragma unroll
        for (int tr = 0; tr < 2; tr++)
            afrag[tr] = *(const short8*)&As[(wm * 32 + tr * 16 + col16) * 40 + quad * 8];
#pragma unroll
        for (int tc = 0; tc < 4; tc++)
            bfrag[tc] = *(const short8*)&Bs[(wn * 64 + tc * 16 + col16) * 40 + quad * 8];
#pragma unroll
        for (int tr = 0; tr < 2; tr++)
#pragma unroll
            for (int tc = 0; tc < 4; tc++)
                acc[tr][tc] = __builtin_amdgcn_mfma_f32_16x16x32_bf16(afrag[tr], bfrag[tc], acc[tr][tc], 0, 0, 0);
        __syncthreads();
    }

#pragma unroll
    for (int tr = 0; tr < 2; tr++) {
#pragma unroll
        for (int tc = 0; tc < 4; tc++) {
            int colg = n0 + wn * 64 + tc * 16 + col16;
            int bidx = MAPN ? lstm_colmap(colg) : colg;
            float bv = bias[bidx];
#pragma unroll
            for (int r = 0; r < 4; r++) {
                int rowg = m0 + wm * 32 + tr * 16 + quad * 4 + r;
                float v = acc[tr][tc][r] + bv;
                if constexpr (__is_same(OutT, float)) {
                    out[(size_t)rowg * N + colg] = v;       // f32 harness output
                } else {
                    out[(size_t)rowg * N + colg] = f2bf(v); // bf16 internal
                }
            }
        }
    }
}

// ---------------------------------------------------------------------------
// One LSTM step: gated[b][n'] = h_prev @ Wh_t[n'] + eproj[msg[b,t]][n']  (bias folded in eproj)
// then fused gate activation + (c,h) update.  N'=4096 gate-interleaved, K=1024.
__global__ __launch_bounds__(256) void lstm_step_k(
    const short* __restrict__ h_prev,          // [512,1024] bf16
    const short* __restrict__ Wh_t,            // [4096,1024] bf16, n' reordered
    const short* __restrict__ eproj,           // [1024,4096] bf16, n' reordered, bias folded
    const int*  __restrict__ msg,              // [512,128]
    int t,
    float* __restrict__ c,                     // [512,1024] f32 state
    short* __restrict__ h_next)                // [512,1024] bf16
{
    constexpr int K = HID;
    __shared__ __align__(16) short As[64 * 40];
    __shared__ __align__(16) short Bs[128 * 40];
    const int tid  = threadIdx.x;
    const int lane = tid & 63;
    const int wid  = tid >> 6;
    const int wm = wid >> 1, wn = wid & 1;
    const int col16 = lane & 15, quad = lane >> 4;
    const int m0 = blockIdx.y * 64;
    const int n0 = blockIdx.x * 128;

    // Issue the embed_proj gathers up-front; consumed after the K-loop.
    float ginit[2][4][4];
#pragma unroll
    for (int tr = 0; tr < 2; tr++)
#pragma unroll
        for (int r = 0; r < 4; r++) {
            int b = m0 + wm * 32 + tr * 16 + quad * 4 + r;
            int v = msg[b * TT + t];
            const short* ep = eproj + (size_t)v * FOURH + n0 + wn * 64 + col16;
#pragma unroll
            for (int tc = 0; tc < 4; tc++) ginit[tr][tc][r] = bf2f(ep[tc * 16]);
        }

    f32x4 acc[2][4];
#pragma unroll
    for (int i = 0; i < 2; i++)
#pragma unroll
        for (int j = 0; j < 4; j++) acc[i][j] = (f32x4)0.0f;

    const int arow = tid >> 2, aq = tid & 3;
    const int brow = tid >> 1, bh = tid & 1;

    for (int k0 = 0; k0 < K; k0 += 32) {
        short8 av  = *(const short8*)(h_prev + (size_t)(m0 + arow) * K + k0 + aq * 8);
        short8 bv0 = *(const short8*)(Wh_t  + (size_t)(n0 + brow) * K + k0 + bh * 16);
        short8 bv1 = *(const short8*)(Wh_t  + (size_t)(n0 + brow) * K + k0 + bh * 16 + 8);
        *(short8*)&As[arow * 40 + aq * 8]      = av;
        *(short8*)&Bs[brow * 40 + bh * 16]     = bv0;
        *(short8*)&Bs[brow * 40 + bh * 16 + 8] = bv1;
        __syncthreads();
        short8 afrag[2], bfrag[4];
#pragma unroll
        for (int tr = 0; tr < 2; tr++)
            afrag[tr] = *(const short8*)&As[(wm * 32 + tr * 16 + col16) * 40 + quad * 8];
#pragma unroll
        for (int tc = 0; tc < 4; tc++)
            bfrag[tc] = *(const short8*)&Bs[(wn * 64 + tc * 16 + col16) * 40 + quad * 8];
#pragma unroll
        for (int tr = 0; tr < 2; tr++)
#pragma unroll
            for (int tc = 0; tc < 4; tc++)
                acc[tr][tc] = __builtin_amdgcn_mfma_f32_16x16x32_bf16(afrag[tr], bfrag[tc], acc[tr][tc], 0, 0, 0);
        __syncthreads();
    }

    // Fused LSTM cell update. tc == gate {i,g,f,o}; hidden unit j shared across tc per lane.
    const int G = (n0 + wn * 64) >> 6;
    const int j = G * 16 + col16;
#pragma unroll
    for (int tr = 0; tr < 2; tr++) {
#pragma unroll
        for (int r = 0; r < 4; r++) {
            int b = m0 + wm * 32 + tr * 16 + quad * 4 + r;
            float i_ = acc[tr][0][r] + ginit[tr][0][r];
            float g_ = acc[tr][1][r] + ginit[tr][1][r];
            float f_ = acc[tr][2][r] + ginit[tr][2][r];
            float o_ = acc[tr][3][r] + ginit[tr][3][r];
            size_t idx = (size_t)b * HID + j;
            float c_old = c[idx];
            float cn = sigmoidf_(f_ + 1.0f) * c_old + sigmoidf_(i_) * tanhf(g_);
            c[idx] = cn;
            float h = sigmoidf_(o_) * tanhf(cn);
            h_next[idx] = f2bf(h);
        }
    }
}

// ---------------------------------------------------------------------------
extern "C" void kernel_launch(void* const* d_in, const int* in_sizes, int n_in,
                              void* d_out, int out_size, void* d_ws, size_t ws_size,
                              hipStream_t stream) {
    const float* images = (const float*)d_in[0];   // [512,2048] f32
    const float* embed  = (const float*)d_in[1];   // [1024,512] f32
    const float* Wcell  = (const float*)d_in[2];   // [1536,4096] f32
    const float* bcell  = (const float*)d_in[3];   // [4096] f32
    const float* Wimg   = (const float*)d_in[4];   // [2048,1024] f32
    const float* bimg   = (const float*)d_in[5];   // [1024] f32
    const float* Whid   = (const float*)d_in[6];   // [1024,1024] f32
    const float* bhid   = (const float*)d_in[7];   // [1024] f32
    const int*   msg    = (const int*)d_in[8];     // [512,128] int32

    float* out0 = (float*)d_out;                   // images_encoded [512,1024] f32
    float* out1 = out0 + (size_t)BB * OUTN;        // hidden_encoded [512,1024] f32

    // Workspace: 20 MB total
    char* ws = (char*)d_ws;
    short* Wh_t  = (short*)(ws);                                  //  8 MB [4096][1024] bf16
    short* eproj = (short*)(ws + (size_t)8  * 1024 * 1024);       //  8 MB [1024][4096] bf16
    short* h_a   = (short*)(ws + (size_t)16 * 1024 * 1024);       //  1 MB
    short* h_b   = (short*)(ws + (size_t)17 * 1024 * 1024);       //  1 MB
    float* cbuf  = (float*)(ws + (size_t)18 * 1024 * 1024);       //  2 MB

    // Recurrent weight: transpose + gate-interleave + bf16 (f32 source, h-rows of W_cell)
    build_wht_k<<<dim3((FOURH * HID) / 256), dim3(256), 0, stream>>>(
        Wcell + (size_t)EMBD * FOURH, Wh_t, FOURH * HID);

    // eproj[v][n'] = bf16(embed_table @ W_cell_x + b_cell), gate-interleaved
    gemm_f32b_k<float, short, true><<<dim3(FOURH / 128, VOC / 64), dim3(256), 0, stream>>>(
        embed, Wcell, bcell, eproj, EMBD, FOURH, FOURH);

    // images_encoded = images @ W_img + b_img (independent of the scan), f32 out
    gemm_f32b_k<float, float, false><<<dim3(OUTN / 128, BB / 64), dim3(256), 0, stream>>>(
        images, Wimg, bimg, out0, DIMG, OUTN, OUTN);

    // state init (ws is poisoned before every timed call)
    init_k<<<dim3((BB * HID) / 256), dim3(256), 0, stream>>>(cbuf, h_a, BB * HID);

    // 128 sequential LSTM steps, ping-pong h buffers (t=127 writes h_a)
    for (int t = 0; t < TT; t++) {
        const short* hp = (t & 1) ? h_b : h_a;
        short* hn       = (t & 1) ? h_a : h_b;
        lstm_step_k<<<dim3(FOURH / 128, BB / 64), dim3(256), 0, stream>>>(
            hp, Wh_t, eproj, msg, t, cbuf, hn);
    }

    // hidden_encoded = h_final @ W_hid + b_hid, f32 out
    gemm_f32b_k<short, float, false><<<dim3(OUTN / 128, BB / 64), dim3(256), 0, stream>>>(
        h_a, Whid, bhid, out1, HID, OUTN, OUTN);
}